// Round 10
// baseline (2629.165 us; speedup 1.0000x reference)
//
#include <hip/hip_runtime.h>
#include <hip/hip_bf16.h>
#include <math.h>
#include <stdio.h>

typedef unsigned short u16;
typedef unsigned int u32;
typedef __attribute__((ext_vector_type(8))) short short8;   // bf16x8 fragment
typedef __attribute__((ext_vector_type(4))) float float4v;  // fp32x4 accumulator
typedef __attribute__((ext_vector_type(4))) u32  uint4v;    // 16B vector
typedef __attribute__((ext_vector_type(2))) u32  uint2v;    // 8B vector

static __device__ __forceinline__ float bf2f(u16 u) {
    return __uint_as_float(((u32)u) << 16);
}
static __device__ __forceinline__ u16 f2bf(float f) {
    u32 x = __float_as_uint(f);
    x += 0x7FFFu + ((x >> 16) & 1u);   // RNE
    return (u16)(x >> 16);
}
static __device__ __forceinline__ float gelu_exact(float x) {
    return 0.5f * x * (1.0f + erff(x * 0.70710678118654752f));
}

// async global->LDS, 16B per lane; LDS dest = wave-uniform base + lane*16 (m97)
static __device__ __forceinline__ void gl2lds16(const u16* g, u16* l) {
    __builtin_amdgcn_global_load_lds(
        (const __attribute__((address_space(1))) u32*)g,
        (__attribute__((address_space(3))) u32*)l, 16, 0, 0);
}

// T = padded tokens per batch (1152 = 9*128), 8 batches -> M = 9216
#define TPAD 1152
#define MPAD (8 * TPAD)

// ---------------------------------------------------------------------------
// dtype probe: bf16 (flag=1) vs fp32 (flag=0) inputs
// ---------------------------------------------------------------------------
__global__ void detect_k(const u32* __restrict__ x, u32* __restrict__ flag) {
    __shared__ int cnt;
    if (threadIdx.x == 0) cnt = 0;
    __syncthreads();
    u32 w = x[threadIdx.x];
    int e = (w >> 7) & 0xFF;
    if (e >= 108 && e <= 134) atomicAdd(&cnt, 1);
    __syncthreads();
    if (threadIdx.x == 0) *flag = (cnt > 128) ? 1u : 0u;
}

__global__ void convert_k(const void* __restrict__ src, u16* __restrict__ dst,
                          long n, const u32* __restrict__ flag) {
    long i = (long)blockIdx.x * 256 + threadIdx.x;
    if (i >= n) return;
    if (*flag) dst[i] = ((const u16*)src)[i];
    else       dst[i] = f2bf(((const float*)src)[i]);
}

// weights -> [N][K] bf16; mode 1 additionally permutes the qkv output dim:
// n = head*768 + f*3 + c3  ->  n' = c3*2048 + head*256 + f
__global__ void transposeT_k(const void* __restrict__ src, u16* __restrict__ dst,
                             int R, int C, int mode, const u32* __restrict__ flag) {
    __shared__ u16 t[32][33];
    int c0 = blockIdx.x * 32, r0 = blockIdx.y * 32;
    long lb = (long)blockIdx.z * R * C;
    int tx = threadIdx.x, ty = threadIdx.y;
    bool isbf = (*flag != 0);
    #pragma unroll
    for (int j = 0; j < 4; ++j) {
        long idx = lb + (long)(r0 + ty + j * 8) * C + (c0 + tx);
        t[ty + j * 8][tx] = isbf ? ((const u16*)src)[idx]
                                 : f2bf(((const float*)src)[idx]);
    }
    __syncthreads();
    #pragma unroll
    for (int j = 0; j < 4; ++j) {
        int c = c0 + ty + j * 8;
        int n = (mode == 1) ? ((c % 3) * 2048 + (c / 768) * 256 + ((c % 768) / 3)) : c;
        dst[lb + (long)n * R + (r0 + tx)] = t[tx][ty + j * 8];
    }
}

__global__ void qkvbias_k(const void* __restrict__ src, u16* __restrict__ dst,
                          const u32* __restrict__ flag) {
    int i = blockIdx.x * 256 + threadIdx.x;   // 6*6144
    int l = i / 6144, n = i % 6144;
    float v = *flag ? bf2f(((const u16*)src)[i]) : ((const float*)src)[i];
    int np = (n % 3) * 2048 + (n / 768) * 256 + ((n % 768) / 3);
    dst[l * 6144 + np] = f2bf(v);
}

// ---------------------------------------------------------------------------
// NT GEMM (round-5 verified): C[M,N] = A[M,K]*B[N,K]^T (+epilogue), BK=64,
// global_load_lds staging, XOR-swizzled LDS, LDS-repacked bf16 epilogues.
// epi: 0 f32 bias | 1 bf16 bias+gelu->mid | 2 f32 bias+gelu
//      3 qkv (permuted cols; Q/K scaled rows, V transposed)
// ---------------------------------------------------------------------------
struct GP {
    const u16 *A, *B, *bias;
    void* C;
    u16 *q, *k, *v;
    long sA, sB, sC;
    int M, N, K, ldC;
    int epi, zoff;
};

#define RPS 136   // repack LDS row stride (u16)

template <int BM, int BN>
__global__ __launch_bounds__(256) void gemmNT_k(GP p) {
    constexpr int MI = BM / 32, NI = BN / 32;
    __shared__ __align__(16) u16 smem[(BM + BN) * 64];
    u16* As = smem;
    u16* Bs = smem + BM * 64;

    const int tid  = threadIdx.x;
    const int lane = tid & 63, wave = tid >> 6;
    const int wr = wave >> 1, wc = wave & 1;
    const int lrow = lane & 15, quad = lane >> 4;
    const int bn0 = blockIdx.x * BN, bm0 = blockIdx.y * BM, bz = blockIdx.z;
    const u16* A = p.A + (long)bz * p.sA;
    const u16* B = p.B + (long)bz * p.sB;
    const int srow = lane >> 3, schk = lane & 7;
    const int sq = ((schk ^ srow) << 3);
    const int K = p.K;

    float4v acc[MI][NI] = {};

    for (int k0 = 0; k0 < K; k0 += 64) {
        #pragma unroll
        for (int j = 0; j < BM / 32; ++j) {
            int m = j * 32 + wave * 8;
            gl2lds16(A + (long)(bm0 + m + srow) * K + k0 + sq, &As[m * 64]);
        }
        #pragma unroll
        for (int j = 0; j < BN / 32; ++j) {
            int n = j * 32 + wave * 8;
            gl2lds16(B + (long)(bn0 + n + srow) * K + k0 + sq, &Bs[n * 64]);
        }
        __syncthreads();

        #pragma unroll
        for (int s = 0; s < 2; ++s) {
            short8 af[MI], bfv[NI];
            #pragma unroll
            for (int mi = 0; mi < MI; ++mi) {
                int m = wr * (BM / 2) + mi * 16 + lrow;
                int c = (s * 4 + quad) ^ (m & 7);
                af[mi] = *(const short8*)&As[m * 64 + c * 8];
            }
            #pragma unroll
            for (int ni = 0; ni < NI; ++ni) {
                int n = wc * (BN / 2) + ni * 16 + lrow;
                int c = (s * 4 + quad) ^ (n & 7);
                bfv[ni] = *(const short8*)&Bs[n * 64 + c * 8];
            }
            #pragma unroll
            for (int mi = 0; mi < MI; ++mi)
                #pragma unroll
                for (int ni = 0; ni < NI; ++ni)
                    acc[mi][ni] = __builtin_amdgcn_mfma_f32_16x16x32_bf16(
                        af[mi], bfv[ni], acc[mi][ni], 0, 0, 0);
        }
        __syncthreads();
    }

    // ---- epilogue ----  C/D layout: col = lane&15, row = quad*4 + r (m89)
    if constexpr (BM == 128 && BN == 128) {
        if (p.epi == 1 || p.epi == 3) {
            u16* rp = smem;            // 64 x RPS repack tile (staging LDS is dead)
            const int c3 = (p.epi == 3) ? (bn0 >> 11) : -1;
            for (int ch = 0; ch < 2; ++ch) {
                if (wr == ch) {
                    #pragma unroll
                    for (int mi = 0; mi < MI; ++mi)
                        #pragma unroll
                        for (int ni = 0; ni < NI; ++ni)
                            #pragma unroll
                            for (int r = 0; r < 4; ++r) {
                                int lr = mi * 16 + quad * 4 + r;
                                int lc = wc * 64 + ni * 16 + lrow;
                                float val = acc[mi][ni][r];
                                if (p.epi == 3) {
                                    val += bf2f(p.bias[bn0 + lc]);
                                    if (c3 < 2) val *= 0.0625f;   // 1/sqrt(256)
                                } else {
                                    val = gelu_exact(val + bf2f(p.bias[bn0 + lc]));
                                }
                                rp[lr * RPS + lc] = f2bf(val);
                            }
                }
                __syncthreads();
                if (p.epi == 3 && c3 == 2) {
                    // V^T out: read tile column-wise -> vT[z][f][t], 16B stores
                    int head = (bn0 & 2047) >> 8, fb = bn0 & 255;
                    int bloc = bm0 / TPAD;
                    int tb = bm0 - bloc * TPAD + ch * 64;
                    long zb = bloc * 8 + head;
                    #pragma unroll
                    for (int pp = 0; pp < 4; ++pp) {
                        int f_l = pp * 32 + (tid >> 3);
                        int t8  = (tid & 7) * 8;
                        union { uint4v v; u16 e[8]; } o;
                        #pragma unroll
                        for (int j = 0; j < 8; ++j) o.e[j] = rp[(t8 + j) * RPS + f_l];
                        *(uint4v*)&p.v[(zb * 256 + fb + f_l) * (long)TPAD + tb + t8] = o.v;
                    }
                } else {
                    #pragma unroll
                    for (int pp = 0; pp < 4; ++pp) {
                        int row_l = pp * 16 + (tid >> 4);
                        int col8  = (tid & 15) * 8;
                        uint4v w = *(const uint4v*)&rp[row_l * RPS + col8];
                        int grow = bm0 + ch * 64 + row_l;
                        u16* base; long dst;
                        if (p.epi == 1) {
                            base = (u16*)p.C;
                            dst = (long)grow * 1024 + bn0 + col8;
                        } else {  // epi 3, Q or K rows
                            int head = (bn0 & 2047) >> 8, fb = bn0 & 255;
                            int bloc = grow / TPAD, t = grow - bloc * TPAD;
                            base = (c3 == 0) ? p.q : p.k;
                            dst = ((long)(bloc * 8 + head) * TPAD + t) * 256 + fb + col8;
                        }
                        *(uint4v*)&base[dst] = w;
                    }
                }
                __syncthreads();
            }
            return;
        }
    }
    // direct f32 path (epi 0 / 2): 16 lanes x 4B = 64B contiguous per quad
    #pragma unroll
    for (int mi = 0; mi < MI; ++mi) {
        #pragma unroll
        for (int ni = 0; ni < NI; ++ni) {
            #pragma unroll
            for (int r = 0; r < 4; ++r) {
                int row = bm0 + wr * (BM / 2) + mi * 16 + quad * 4 + r;
                int col = bn0 + wc * (BN / 2) + ni * 16 + lrow;
                float v2 = acc[mi][ni][r] + bf2f(p.bias[col]);
                if (p.epi == 2) v2 = gelu_exact(v2);
                ((float*)p.C)[(long)row * p.ldC + col] = v2;
            }
        }
    }
}

// ---------------------------------------------------------------------------
// Fused flash-style attention, 2x2 wave tiling (halved LDS fragment traffic).
// Block = 64 Q-rows x one z=(b,head). Wave (wr,wc):
//   QK^T: 32 Q-rows (wr) x 32 kv (wc); PV: 32 Q-rows (wr) x 128 d (wc).
// Q A-frags in registers. K tile (64x256, KR) / V^T tile (256x64, VR) staged
// via global_load_lds; K for iter i+1 prefetched during PV of iter i.
// P is cross-wave per Q-half (xor-swizzled 32x64 tile) -> 3 barriers/iter.
// No-max softmax (|logits| <= ~0.05). Rowsums pair-exchanged at the end.
// XCD swizzle: all 18 q-tiles of one z share blk%8 -> one XCD's L2 holds K/V.
// ---------------------------------------------------------------------------
__global__ __launch_bounds__(256) void flash_k(const u16* __restrict__ qb,
                                               const u16* __restrict__ kb,
                                               const u16* __restrict__ vT,
                                               u16* __restrict__ ao, int zoff) {
    // u16 layout: KR 16384 | VR 16384 | P 2 halves x 2048
    __shared__ __align__(16) u16 smem[16384 + 16384 + 4096];
    u16* KR = smem;
    u16* VR = smem + 16384;

    const int tid  = threadIdx.x;
    const int lane = tid & 63, wave = tid >> 6;
    const int wr = wave >> 1, wc = wave & 1;
    const int lrow = lane & 15, quad = lane >> 4;
    const int srow = lane >> 3, schk = lane & 7;
    const int sq   = ((schk ^ srow) << 3);

    // XCD-colocating swizzle: blk -> (q0, z) with z%8 == blk%8
    const int blk = blockIdx.x;
    const int t_  = blk >> 3;
    const int q0  = (t_ % 18) * 64;
    const int z   = (blk & 7) + 8 * (t_ / 18);
    u16* Ph = smem + 32768 + wr * 2048;    // this Q-half's P tile (32x64, xor)

    const u16* Qp = qb + ((long)z * TPAD + q0) * 256;
    const u16* Kp = kb + (long)z * TPAD * 256;
    const u16* Vp = vT + (long)z * 256 * TPAD;

    // stage Q into KR once, pull A-fragments into registers, release KR
    #pragma unroll
    for (int k0 = 0; k0 < 4; ++k0)
        #pragma unroll
        for (int j = 0; j < 2; ++j) {
            int m = j * 32 + wave * 8;
            gl2lds16(Qp + (long)(m + srow) * 256 + k0 * 64 + sq,
                     &KR[k0 * 4096 + m * 64]);
        }
    __syncthreads();
    short8 qf[16];   // [mi*8 + k0*2 + s] : rows wr*32 + mi*16 + lrow
    #pragma unroll
    for (int mi = 0; mi < 2; ++mi) {
        int m = wr * 32 + mi * 16 + lrow;
        #pragma unroll
        for (int k0 = 0; k0 < 4; ++k0)
            #pragma unroll
            for (int s = 0; s < 2; ++s)
                qf[mi * 8 + k0 * 2 + s] = *(const short8*)&KR[k0 * 4096 + m * 64
                                + (((s * 4 + quad) ^ (m & 7)) << 3)];
    }
    __syncthreads();   // all waves' qf reads done before KR reuse

    // initial K0 + V0 staging
    #pragma unroll
    for (int c = 0; c < 4; ++c)
        #pragma unroll
        for (int j = 0; j < 2; ++j) {
            int n = j * 32 + wave * 8;
            gl2lds16(Kp + (long)(n + srow) * 256 + c * 64 + sq,
                     &KR[c * 4096 + n * 64]);
            gl2lds16(Vp + (long)(c * 64 + n + srow) * TPAD + sq,
                     &VR[c * 4096 + n * 64]);
        }

    float4v Oacc[2][8] = {};   // [mi][ni]: rows wr*32+mi*16+quad*4+r, cols wc*128+ni*16+lrow
    float   lacc[8] = {};      // [mi*4+r] partial rowsum over this wave's kv cols

    for (int kv = 0; kv < TPAD; kv += 64) {
        __syncthreads();   // K/V deposits for this iter drained; KR/VR free of old readers

        // QK^T: A from registers, B from KR (cols wc*32 + ni*16 + lrow)
        float4v Sacc[2][2] = {};
        #pragma unroll
        for (int k0 = 0; k0 < 4; ++k0)
            #pragma unroll
            for (int s = 0; s < 2; ++s) {
                short8 bfv[2];
                #pragma unroll
                for (int ni = 0; ni < 2; ++ni) {
                    int n = wc * 32 + ni * 16 + lrow;
                    bfv[ni] = *(const short8*)&KR[k0 * 4096 + n * 64
                                + (((s * 4 + quad) ^ (n & 7)) << 3)];
                }
                #pragma unroll
                for (int mi = 0; mi < 2; ++mi)
                    #pragma unroll
                    for (int ni = 0; ni < 2; ++ni)
                        Sacc[mi][ni] = __builtin_amdgcn_mfma_f32_16x16x32_bf16(
                            qf[mi * 8 + k0 * 2 + s], bfv[ni], Sacc[mi][ni], 0, 0, 0);
            }

        // exp + partial rowsum + P -> Q-half LDS tile (xor-chunked 32x64)
        #pragma unroll
        for (int mi = 0; mi < 2; ++mi)
            #pragma unroll
            for (int r = 0; r < 4; ++r) {
                int rowL = mi * 16 + quad * 4 + r;
                float rs = 0.0f;
                #pragma unroll
                for (int ni = 0; ni < 2; ++ni) {
                    int colL = wc * 32 + ni * 16 + lrow;
                    float e = (kv + colL < 1026) ? __expf(Sacc[mi][ni][r]) : 0.0f;
                    int chunk = (colL >> 3) ^ (rowL & 7);
                    Ph[rowL * 64 + chunk * 8 + (lrow & 7)] = f2bf(e);
                    rs += e;
                }
                rs += __shfl_xor(rs, 1, 64);
                rs += __shfl_xor(rs, 2, 64);
                rs += __shfl_xor(rs, 4, 64);
                rs += __shfl_xor(rs, 8, 64);
                lacc[mi * 4 + r] += rs;
            }
        __syncthreads();   // P visible across the Q-half pair; KR reads all done

        // prefetch next K tile into KR (overlaps PV)
        if (kv + 64 < TPAD) {
            #pragma unroll
            for (int c = 0; c < 4; ++c)
                #pragma unroll
                for (int j = 0; j < 2; ++j) {
                    int n = j * 32 + wave * 8;
                    gl2lds16(Kp + (long)(kv + 64 + n + srow) * 256 + c * 64 + sq,
                             &KR[c * 4096 + n * 64]);
                }
        }

        // PV: A = P (this Q-half), B = V^T from VR; O rows wr*32.., cols wc*128..
        #pragma unroll
        for (int w = 0; w < 2; ++w)
            #pragma unroll
            for (int mi = 0; mi < 2; ++mi) {
                int rowL = mi * 16 + lrow;
                short8 af = *(const short8*)&Ph[rowL * 64
                            + (((w * 4 + quad) ^ (rowL & 7)) << 3)];
                #pragma unroll
                for (int ni = 0; ni < 8; ++ni) {
                    int d = wc * 128 + ni * 16 + lrow;
                    int c = d >> 6, dl = d & 63;
                    short8 bf = *(const short8*)&VR[c * 4096 + dl * 64
                                + (((w * 4 + quad) ^ (dl & 7)) << 3)];
                    Oacc[mi][ni] = __builtin_amdgcn_mfma_f32_16x16x32_bf16(
                        af, bf, Oacc[mi][ni], 0, 0, 0);
                }
            }
        __syncthreads();   // VR reads done (also drains the K prefetch)

        // stage next V tile into VR
        if (kv + 64 < TPAD) {
            #pragma unroll
            for (int c = 0; c < 4; ++c)
                #pragma unroll
                for (int j = 0; j < 2; ++j) {
                    int n = j * 32 + wave * 8;
                    gl2lds16(Vp + (long)(c * 64 + n + srow) * TPAD + kv + 64 + sq,
                             &VR[c * 4096 + n * 64]);
                }
        }
    }

    // rowsum pair-exchange (wc 0/1 partials) via P region (dead)
    float* Lex = (float*)(smem + 32768);   // [64 rows][2 wc]
    #pragma unroll
    for (int mi = 0; mi < 2; ++mi)
        #pragma unroll
        for (int r = 0; r < 4; ++r) {
            int row = wr * 32 + mi * 16 + quad * 4 + r;
            if (lrow == 0) Lex[row * 2 + wc] = lacc[mi * 4 + r];
        }
    __syncthreads();
    float linv[8];
    #pragma unroll
    for (int mi = 0; mi < 2; ++mi)
        #pragma unroll
        for (int r = 0; r < 4; ++r) {
            int row = wr * 32 + mi * 16 + quad * 4 + r;
            linv[mi * 4 + r] = 1.0f / (Lex[row * 2] + Lex[row * 2 + 1]);
        }

    // epilogue: O/l -> LDS repack -> coalesced 16B stores into ao
    u16* out = smem;    // 64 x 264 (33 KB, within dead KR+VR)
    #pragma unroll
    for (int mi = 0; mi < 2; ++mi)
        #pragma unroll
        for (int ni = 0; ni < 8; ++ni)
            #pragma unroll
            for (int r = 0; r < 4; ++r) {
                int row = wr * 32 + mi * 16 + quad * 4 + r;
                int col = wc * 128 + ni * 16 + lrow;
                out[row * 264 + col] = f2bf(Oacc[mi][ni][r] * linv[mi * 4 + r]);
            }
    __syncthreads();
    int zg = zoff + z;
    int b = zg >> 3, head = zg & 7;
    #pragma unroll
    for (int pp = 0; pp < 8; ++pp) {
        int row  = pp * 8 + (tid >> 5);
        int col8 = (tid & 31) * 8;
        uint4v w = *(const uint4v*)&out[row * 264 + col8];
        *(uint4v*)&ao[((long)(b * TPAD) + q0 + row) * 2048 + head * 256 + col8] = w;
    }
}

// ---------------------------------------------------------------------------
// LayerNorm: one wave per row of 256, fp32 in -> bf16 out
// ---------------------------------------------------------------------------
__global__ __launch_bounds__(256) void ln_k(const float* __restrict__ h,
                                            const u16* __restrict__ g,
                                            const u16* __restrict__ b,
                                            u16* __restrict__ out, int M) {
    int row  = blockIdx.x * 4 + (threadIdx.x >> 6);
    int lane = threadIdx.x & 63;
    if (row >= M) return;
    const float* x = h + (long)row * 256;
    float4v v = *(const float4v*)(x + lane * 4);
    float s  = v[0] + v[1] + v[2] + v[3];
    float s2 = v[0] * v[0] + v[1] * v[1] + v[2] * v[2] + v[3] * v[3];
    #pragma unroll
    for (int off = 32; off; off >>= 1) {
        s  += __shfl_xor(s, off, 64);
        s2 += __shfl_xor(s2, off, 64);
    }
    float mean = s * (1.0f / 256.0f);
    float var  = s2 * (1.0f / 256.0f) - mean * mean;
    float rs   = rsqrtf(var + 1e-5f);
    union { uint2v v; u16 e[4]; } o;
    #pragma unroll
    for (int j = 0; j < 4; ++j) {
        int c = lane * 4 + j;
        o.e[j] = f2bf((v[j] - mean) * rs * bf2f(g[c]) + bf2f(b[c]));
    }
    *(uint2v*)&out[(long)row * 256 + lane * 4] = o.v;
}

// ---------------------------------------------------------------------------
__global__ void embed_k(const u16* __restrict__ x, const u16* __restrict__ cls,
                        const u16* __restrict__ dict, float* __restrict__ h) {
    long i = (long)blockIdx.x * 256 + threadIdx.x;
    int d = i & 255;
    long row = i >> 8;
    int b = (int)(row / TPAD), t = (int)(row - (long)b * TPAD);
    float v;
    if (t < 1024)       v = bf2f(x[((long)b * 1024 + t) * 256 + d]);
    else if (t == 1024) v = bf2f(cls[d]);
    else if (t == 1025) v = bf2f(dict[d]);
    else                v = 0.0f;   // pad rows: zero (finite through LN)
    h[i] = v;
}

__global__ void outconv_k(const float* __restrict__ h, void* __restrict__ out,
                          const u32* __restrict__ flag) {
    long i = (long)blockIdx.x * 256 + threadIdx.x;
    int d = i & 255;
    long row = i >> 8;
    int b = (int)(row / TPAD), t = (int)(row - (long)b * TPAD);
    long o;
    if (t < 1024)       o = ((long)b * 1024 + t) * 256 + d;
    else if (t == 1024) o = 8L * 1024 * 256 + (long)b * 256 + d;
    else if (t == 1025) o = 8L * 1024 * 256 + 8L * 256 + (long)b * 256 + d;
    else return;
    float v = h[i];
    if (*flag) ((u16*)out)[o] = f2bf(v);
    else       ((float*)out)[o] = v;
}

// ---------------------------------------------------------------------------
template <int BM, int BN>
static void launch_gemm(hipStream_t s, const GP& p, int nz) {
    dim3 grid(p.N / BN, p.M / BM, nz);
    gemmNT_k<BM, BN><<<grid, dim3(256), 0, s>>>(p);
}

extern "C" void kernel_launch(void* const* d_in, const int* in_sizes, int n_in,
                              void* d_out, int out_size, void* d_ws, size_t ws_size,
                              hipStream_t stream) {
    char* ws = (char*)d_ws;
    size_t used = 0;
    auto alloc = [&](size_t bytes) {
        char* ptr = ws + used;
        used += (bytes + 255) & ~(size_t)255;
        return ptr;
    };
    u32* flag = (u32*)alloc(256);

    // plain bf16 canon for non-weight inputs (qkv bias handled separately)
    static const int plainIdx[10] = {0, 1, 2, 3, 4, 8, 9, 10, 12, 14};
    u16* cp[15] = {};
    for (int j = 0; j < 10; ++j) {
        int i = plainIdx[j];
        cp[i] = (u16*)alloc((size_t)in_sizes[i] * 2);
    }
    u16* qkv_bP  = (u16*)alloc(6L * 6144 * 2);          // permuted bias
    u16* qkv_wT  = (u16*)alloc(6L * 6144 * 256 * 2);    // permuted+transposed
    u16* proj_wT = (u16*)alloc(6L * 256 * 2048 * 2);
    u16* w1T     = (u16*)alloc(6L * 1024 * 256 * 2);
    u16* w2T     = (u16*)alloc(6L * 256 * 1024 * 2);

    float* h  = (float*)alloc((size_t)MPAD * 256 * 4);
    u16*   hn = (u16*)  alloc((size_t)MPAD * 256 * 2);
    u16*   ao = (u16*)  alloc((size_t)MPAD * 2048 * 2);
    u16*   mid= (u16*)  alloc((size_t)MPAD * 1024 * 2);

    // attention group size G (batches per group), adaptive to ws_size
    const size_t perB = (size_t)8 * 3L * TPAD * 256 * 2;   // q + k + vT per batch
    int G = 8;
    while (G > 1 && used + (size_t)G * perB + 8192 > ws_size) G >>= 1;
    u16* qb = (u16*)alloc((size_t)G * 8 * TPAD * 256 * 2);
    u16* kb = (u16*)alloc((size_t)G * 8 * TPAD * 256 * 2);
    u16* vT = (u16*)alloc((size_t)G * 8 * 256 * TPAD * 2);
    if (used > ws_size) {
        fprintf(stderr, "kernel_launch: need %zu ws bytes, have %zu\n", used, ws_size);
        return;
    }

    detect_k<<<1, 256, 0, stream>>>((const u32*)d_in[0], flag);
    for (int j = 0; j < 10; ++j) {
        int i = plainIdx[j];
        long n = in_sizes[i];
        convert_k<<<(int)((n + 255) / 256), 256, 0, stream>>>(d_in[i], cp[i], n, flag);
    }
    qkvbias_k<<<6 * 6144 / 256, 256, 0, stream>>>(d_in[6], qkv_bP, flag);
    transposeT_k<<<dim3(6144/32, 256/32, 6), dim3(32, 8), 0, stream>>>(d_in[5],  qkv_wT,  256,  6144, 1, flag);
    transposeT_k<<<dim3(256/32, 2048/32, 6), dim3(32, 8), 0, stream>>>(d_in[7],  proj_wT, 2048, 256,  0, flag);
    transposeT_k<<<dim3(1024/32, 256/32, 6), dim3(32, 8), 0, stream>>>(d_in[11], w1T,     256,  1024, 0, flag);
    transposeT_k<<<dim3(256/32, 1024/32, 6), dim3(32, 8), 0, stream>>>(d_in[13], w2T,     1024, 256,  0, flag);

    embed_k<<<MPAD, 256, 0, stream>>>(cp[0], cp[1], cp[2], h);

    const int nGroups = 8 / G;
    for (int l = 0; l < 6; ++l) {
        ln_k<<<MPAD / 4, 256, 0, stream>>>(h, cp[3] + l * 256, cp[4] + l * 256, hn, MPAD);

        for (int g = 0; g < nGroups; ++g) {
            {   // QKV: [G*1152, 256] x [6144, 256]^T -> Q/K rows, V^T
                GP p{};
                p.A = hn + (long)g * G * TPAD * 256;
                p.B = qkv_wT + (long)l * 6144 * 256;
                p.bias = qkv_bP + l * 6144;
                p.M = G * TPAD; p.N = 6144; p.K = 256;
                p.epi = 3; p.q = qb; p.k = kb; p.v = vT;
                launch_gemm<128, 128>(stream, p, 1);
            }
            // fused attention: 18 q-tiles x G*8 heads, XCD-swizzled 1D grid
            flash_k<<<dim3(18 * G * 8), dim3(256), 0, stream>>>(
                qb, kb, vT, ao, g * G * 8);
        }
        {   // proj: h = ao @ proj_w + b (fp32, 64x64 tiles: 576 blocks)
            GP p{};
            p.A = ao; p.B = proj_wT + (long)l * 256 * 2048;
            p.bias = cp[8] + l * 256;
            p.C = h; p.ldC = 256;
            p.M = MPAD; p.N = 256; p.K = 2048;
            p.epi = 0;
            launch_gemm<64, 64>(stream, p, 1);
        }
        ln_k<<<MPAD / 4, 256, 0, stream>>>(h, cp[9] + l * 256, cp[10] + l * 256, hn, MPAD);
        {   // mlp1: mid = gelu(hn @ w1 + b1) (bf16, repacked stores)
            GP p{};
            p.A = hn; p.B = w1T + (long)l * 1024 * 256;
            p.bias = cp[12] + l * 1024;
            p.C = mid;
            p.M = MPAD; p.N = 1024; p.K = 256;
            p.epi = 1;
            launch_gemm<128, 128>(stream, p, 1);
        }
        {   // mlp2: h = gelu(mid @ w2 + b2) (fp32, 64x64 tiles: 576 blocks)
            GP p{};
            p.A = mid; p.B = w2T + (long)l * 256 * 1024;
            p.bias = cp[14] + l * 256;
            p.C = h; p.ldC = 256;
            p.M = MPAD; p.N = 256; p.K = 1024;
            p.epi = 2;
            launch_gemm<64, 64>(stream, p, 1);
        }
    }

    outconv_k<<<MPAD, 256, 0, stream>>>(h, d_out, flag);
}

// Round 11
// 2195.438 us; speedup vs baseline: 1.1976x; 1.1976x over previous
//
#include <hip/hip_runtime.h>
#include <hip/hip_bf16.h>
#include <math.h>
#include <stdio.h>

typedef unsigned short u16;
typedef unsigned int u32;
typedef __attribute__((ext_vector_type(8))) short short8;   // bf16x8 fragment
typedef __attribute__((ext_vector_type(4))) float float4v;  // fp32x4 accumulator
typedef __attribute__((ext_vector_type(4))) u32  uint4v;    // 16B vector
typedef __attribute__((ext_vector_type(2))) u32  uint2v;    // 8B vector

static __device__ __forceinline__ float bf2f(u16 u) {
    return __uint_as_float(((u32)u) << 16);
}
static __device__ __forceinline__ u16 f2bf(float f) {
    u32 x = __float_as_uint(f);
    x += 0x7FFFu + ((x >> 16) & 1u);   // RNE
    return (u16)(x >> 16);
}
static __device__ __forceinline__ float gelu_exact(float x) {
    return 0.5f * x * (1.0f + erff(x * 0.70710678118654752f));
}

// async global->LDS, 16B per lane; LDS dest = wave-uniform base + lane*16 (m97)
static __device__ __forceinline__ void gl2lds16(const u16* g, u16* l) {
    __builtin_amdgcn_global_load_lds(
        (const __attribute__((address_space(1))) u32*)g,
        (__attribute__((address_space(3))) u32*)l, 16, 0, 0);
}

// wait LDS ops retired (gfx9 encoding: lgkmcnt=0, vmcnt=63, expcnt=7)
static __device__ __forceinline__ void wait_lds() {
#if __has_builtin(__builtin_amdgcn_s_waitcnt)
    __builtin_amdgcn_s_waitcnt(0xC07F);
#else
    __syncthreads();
#endif
}

// T = padded tokens per batch (1152 = 9*128), 8 batches -> M = 9216
#define TPAD 1152
#define MPAD (8 * TPAD)

// ---------------------------------------------------------------------------
// dtype probe: bf16 (flag=1) vs fp32 (flag=0) inputs
// ---------------------------------------------------------------------------
__global__ void detect_k(const u32* __restrict__ x, u32* __restrict__ flag) {
    __shared__ int cnt;
    if (threadIdx.x == 0) cnt = 0;
    __syncthreads();
    u32 w = x[threadIdx.x];
    int e = (w >> 7) & 0xFF;
    if (e >= 108 && e <= 134) atomicAdd(&cnt, 1);
    __syncthreads();
    if (threadIdx.x == 0) *flag = (cnt > 128) ? 1u : 0u;
}

__global__ void convert_k(const void* __restrict__ src, u16* __restrict__ dst,
                          long n, const u32* __restrict__ flag) {
    long i = (long)blockIdx.x * 256 + threadIdx.x;
    if (i >= n) return;
    if (*flag) dst[i] = ((const u16*)src)[i];
    else       dst[i] = f2bf(((const float*)src)[i]);
}

// weights -> [N][K] bf16; mode 1 additionally permutes the qkv output dim:
// n = head*768 + f*3 + c3  ->  n' = c3*2048 + head*256 + f
__global__ void transposeT_k(const void* __restrict__ src, u16* __restrict__ dst,
                             int R, int C, int mode, const u32* __restrict__ flag) {
    __shared__ u16 t[32][33];
    int c0 = blockIdx.x * 32, r0 = blockIdx.y * 32;
    long lb = (long)blockIdx.z * R * C;
    int tx = threadIdx.x, ty = threadIdx.y;
    bool isbf = (*flag != 0);
    #pragma unroll
    for (int j = 0; j < 4; ++j) {
        long idx = lb + (long)(r0 + ty + j * 8) * C + (c0 + tx);
        t[ty + j * 8][tx] = isbf ? ((const u16*)src)[idx]
                                 : f2bf(((const float*)src)[idx]);
    }
    __syncthreads();
    #pragma unroll
    for (int j = 0; j < 4; ++j) {
        int c = c0 + ty + j * 8;
        int n = (mode == 1) ? ((c % 3) * 2048 + (c / 768) * 256 + ((c % 768) / 3)) : c;
        dst[lb + (long)n * R + (r0 + tx)] = t[tx][ty + j * 8];
    }
}

__global__ void qkvbias_k(const void* __restrict__ src, u16* __restrict__ dst,
                          const u32* __restrict__ flag) {
    int i = blockIdx.x * 256 + threadIdx.x;   // 6*6144
    int l = i / 6144, n = i % 6144;
    float v = *flag ? bf2f(((const u16*)src)[i]) : ((const float*)src)[i];
    int np = (n % 3) * 2048 + (n / 768) * 256 + ((n % 768) / 3);
    dst[l * 6144 + np] = f2bf(v);
}

// ---------------------------------------------------------------------------
// NT GEMM (round-5 verified): C[M,N] = A[M,K]*B[N,K]^T (+epilogue), BK=64,
// global_load_lds staging, XOR-swizzled LDS, LDS-repacked bf16 epilogues.
// epi: 0 f32 bias | 1 bf16 bias+gelu->mid | 2 f32 bias+gelu
//      3 qkv (permuted cols; Q/K scaled rows, V transposed)
// ---------------------------------------------------------------------------
struct GP {
    const u16 *A, *B, *bias;
    void* C;
    u16 *q, *k, *v;
    long sA, sB, sC;
    int M, N, K, ldC;
    int epi, zoff;
};

#define RPS 136   // repack LDS row stride (u16)

template <int BM, int BN>
__global__ __launch_bounds__(256) void gemmNT_k(GP p) {
    constexpr int MI = BM / 32, NI = BN / 32;
    __shared__ __align__(16) u16 smem[(BM + BN) * 64];
    u16* As = smem;
    u16* Bs = smem + BM * 64;

    const int tid  = threadIdx.x;
    const int lane = tid & 63, wave = tid >> 6;
    const int wr = wave >> 1, wc = wave & 1;
    const int lrow = lane & 15, quad = lane >> 4;
    const int bn0 = blockIdx.x * BN, bm0 = blockIdx.y * BM, bz = blockIdx.z;
    const u16* A = p.A + (long)bz * p.sA;
    const u16* B = p.B + (long)bz * p.sB;
    const int srow = lane >> 3, schk = lane & 7;
    const int sq = ((schk ^ srow) << 3);
    const int K = p.K;

    float4v acc[MI][NI] = {};

    for (int k0 = 0; k0 < K; k0 += 64) {
        #pragma unroll
        for (int j = 0; j < BM / 32; ++j) {
            int m = j * 32 + wave * 8;
            gl2lds16(A + (long)(bm0 + m + srow) * K + k0 + sq, &As[m * 64]);
        }
        #pragma unroll
        for (int j = 0; j < BN / 32; ++j) {
            int n = j * 32 + wave * 8;
            gl2lds16(B + (long)(bn0 + n + srow) * K + k0 + sq, &Bs[n * 64]);
        }
        __syncthreads();

        #pragma unroll
        for (int s = 0; s < 2; ++s) {
            short8 af[MI], bfv[NI];
            #pragma unroll
            for (int mi = 0; mi < MI; ++mi) {
                int m = wr * (BM / 2) + mi * 16 + lrow;
                int c = (s * 4 + quad) ^ (m & 7);
                af[mi] = *(const short8*)&As[m * 64 + c * 8];
            }
            #pragma unroll
            for (int ni = 0; ni < NI; ++ni) {
                int n = wc * (BN / 2) + ni * 16 + lrow;
                int c = (s * 4 + quad) ^ (n & 7);
                bfv[ni] = *(const short8*)&Bs[n * 64 + c * 8];
            }
            #pragma unroll
            for (int mi = 0; mi < MI; ++mi)
                #pragma unroll
                for (int ni = 0; ni < NI; ++ni)
                    acc[mi][ni] = __builtin_amdgcn_mfma_f32_16x16x32_bf16(
                        af[mi], bfv[ni], acc[mi][ni], 0, 0, 0);
        }
        __syncthreads();
    }

    // ---- epilogue ----  C/D layout: col = lane&15, row = quad*4 + r (m89)
    if constexpr (BM == 128 && BN == 128) {
        if (p.epi == 1 || p.epi == 3) {
            u16* rp = smem;            // 64 x RPS repack tile (staging LDS is dead)
            const int c3 = (p.epi == 3) ? (bn0 >> 11) : -1;
            for (int ch = 0; ch < 2; ++ch) {
                if (wr == ch) {
                    #pragma unroll
                    for (int mi = 0; mi < MI; ++mi)
                        #pragma unroll
                        for (int ni = 0; ni < NI; ++ni)
                            #pragma unroll
                            for (int r = 0; r < 4; ++r) {
                                int lr = mi * 16 + quad * 4 + r;
                                int lc = wc * 64 + ni * 16 + lrow;
                                float val = acc[mi][ni][r];
                                if (p.epi == 3) {
                                    val += bf2f(p.bias[bn0 + lc]);
                                    if (c3 < 2) val *= 0.0625f;   // 1/sqrt(256)
                                } else {
                                    val = gelu_exact(val + bf2f(p.bias[bn0 + lc]));
                                }
                                rp[lr * RPS + lc] = f2bf(val);
                            }
                }
                __syncthreads();
                if (p.epi == 3 && c3 == 2) {
                    // V^T out: read tile column-wise -> vT[z][f][t], 16B stores
                    int head = (bn0 & 2047) >> 8, fb = bn0 & 255;
                    int bloc = bm0 / TPAD;
                    int tb = bm0 - bloc * TPAD + ch * 64;
                    long zb = bloc * 8 + head;
                    #pragma unroll
                    for (int pp = 0; pp < 4; ++pp) {
                        int f_l = pp * 32 + (tid >> 3);
                        int t8  = (tid & 7) * 8;
                        union { uint4v v; u16 e[8]; } o;
                        #pragma unroll
                        for (int j = 0; j < 8; ++j) o.e[j] = rp[(t8 + j) * RPS + f_l];
                        *(uint4v*)&p.v[(zb * 256 + fb + f_l) * (long)TPAD + tb + t8] = o.v;
                    }
                } else {
                    #pragma unroll
                    for (int pp = 0; pp < 4; ++pp) {
                        int row_l = pp * 16 + (tid >> 4);
                        int col8  = (tid & 15) * 8;
                        uint4v w = *(const uint4v*)&rp[row_l * RPS + col8];
                        int grow = bm0 + ch * 64 + row_l;
                        u16* base; long dst;
                        if (p.epi == 1) {
                            base = (u16*)p.C;
                            dst = (long)grow * 1024 + bn0 + col8;
                        } else {  // epi 3, Q or K rows
                            int head = (bn0 & 2047) >> 8, fb = bn0 & 255;
                            int bloc = grow / TPAD, t = grow - bloc * TPAD;
                            base = (c3 == 0) ? p.q : p.k;
                            dst = ((long)(bloc * 8 + head) * TPAD + t) * 256 + fb + col8;
                        }
                        *(uint4v*)&base[dst] = w;
                    }
                }
                __syncthreads();
            }
            return;
        }
    }
    // direct f32 path (epi 0 / 2): 16 lanes x 4B = 64B contiguous per quad
    #pragma unroll
    for (int mi = 0; mi < MI; ++mi) {
        #pragma unroll
        for (int ni = 0; ni < NI; ++ni) {
            #pragma unroll
            for (int r = 0; r < 4; ++r) {
                int row = bm0 + wr * (BM / 2) + mi * 16 + quad * 4 + r;
                int col = bn0 + wc * (BN / 2) + ni * 16 + lrow;
                float v2 = acc[mi][ni][r] + bf2f(p.bias[col]);
                if (p.epi == 2) v2 = gelu_exact(v2);
                ((float*)p.C)[(long)row * p.ldC + col] = v2;
            }
        }
    }
}

// ---------------------------------------------------------------------------
// Fused flash-style attention (round-9 verified structure, 2 barriers/iter)
// + XCD-colocating block swizzle (round-10 verified: FETCH 319->70 MB).
// Block = 64 Q-rows of one z=(b,head); 4 waves, each wave owns 16 Q-rows.
// Q fragments in REGISTERS; K tile (64x256) and V^T tile (256x64) staged
// whole into separate LDS regions each kv iteration:
//   stage K+V -> barrier -> 32 QK MFMA -> exp->P(LDS, same-wave) -> 32 PV
//   MFMA -> barrier.
// No-max softmax (|logits| <= ~0.05). O = sum exp(QK)*V ; out = O / rowsum.
// ---------------------------------------------------------------------------
__global__ __launch_bounds__(256) void flash_k(const u16* __restrict__ qb,
                                               const u16* __restrict__ kb,
                                               const u16* __restrict__ vT,
                                               u16* __restrict__ ao, int zoff) {
    // u16 layout: KR 16384 (Q-init / K tiles / epilogue repack) | VR 16384 | P 4608
    __shared__ __align__(16) u16 smem[16384 + 16384 + 4608];
    u16* KR = smem;
    u16* VR = smem + 16384;

    const int tid  = threadIdx.x;
    const int lane = tid & 63, wave = tid >> 6;
    const int lrow = lane & 15, quad = lane >> 4;
    const int srow = lane >> 3, schk = lane & 7;
    const int sq   = ((schk ^ srow) << 3);

    // XCD-colocating swizzle: all 18 q-tiles of one z share blk%8 ->
    // one XCD's L2 serves that z's K/V (hardware maps blocks to XCDs by blk%8)
    const int blk = blockIdx.x;
    const int t_  = blk >> 3;
    const int q0  = (t_ % 18) * 64;
    const int z   = (blk & 7) + 8 * (t_ / 18);
    u16* Plds = smem + 32768 + wave * (16 * 72);

    const u16* Qp = qb + ((long)z * TPAD + q0) * 256;
    const u16* Kp = kb + (long)z * TPAD * 256;
    const u16* Vp = vT + (long)z * 256 * TPAD;

    // stage Q into KR once, pull A-fragments into registers, release KR
    #pragma unroll
    for (int k0 = 0; k0 < 4; ++k0)
        #pragma unroll
        for (int j = 0; j < 2; ++j) {
            int m = j * 32 + wave * 8;
            gl2lds16(Qp + (long)(m + srow) * 256 + k0 * 64 + sq,
                     &KR[k0 * 4096 + m * 64]);
        }
    __syncthreads();
    const int mloc = wave * 16 + lrow;
    short8 qf[8];
    #pragma unroll
    for (int k0 = 0; k0 < 4; ++k0)
        #pragma unroll
        for (int s = 0; s < 2; ++s)
            qf[k0 * 2 + s] = *(const short8*)&KR[k0 * 4096 + mloc * 64
                            + (((s * 4 + quad) ^ (mloc & 7)) << 3)];
    __syncthreads();   // all waves' qf reads done before KR reuse

    float4v Oacc[16] = {};   // [dc*4+ni]: O[row=quad*4+r][dc*64+ni*16+lrow]
    float   lacc[4] = {};    // rowsum for row quad*4+r

    for (int kv = 0; kv < TPAD; kv += 64) {
        // stage full K tile (KR) and full V^T tile (VR) concurrently
        #pragma unroll
        for (int c = 0; c < 4; ++c)
            #pragma unroll
            for (int j = 0; j < 2; ++j) {
                int n = j * 32 + wave * 8;
                gl2lds16(Kp + (long)(kv + n + srow) * 256 + c * 64 + sq,
                         &KR[c * 4096 + n * 64]);
                gl2lds16(Vp + (long)(c * 64 + n + srow) * TPAD + kv + sq,
                         &VR[c * 4096 + n * 64]);
            }
        __syncthreads();   // joint drain of 64 KB of staging

        // QK^T: A from registers, B from KR
        float4v Sacc[4] = {};
        #pragma unroll
        for (int k0 = 0; k0 < 4; ++k0)
            #pragma unroll
            for (int s = 0; s < 2; ++s)
                #pragma unroll
                for (int ni = 0; ni < 4; ++ni) {
                    int n = ni * 16 + lrow;
                    short8 bf = *(const short8*)&KR[k0 * 4096 + n * 64
                                + (((s * 4 + quad) ^ (n & 7)) << 3)];
                    Sacc[ni] = __builtin_amdgcn_mfma_f32_16x16x32_bf16(
                        qf[k0 * 2 + s], bf, Sacc[ni], 0, 0, 0);
                }

        // exp + rowsum + P -> per-wave LDS (C-layout -> A-layout)
        #pragma unroll
        for (int r = 0; r < 4; ++r) {
            float rs = 0.0f;
            #pragma unroll
            for (int ni = 0; ni < 4; ++ni) {
                int col = kv + ni * 16 + lrow;
                float e = (col < 1026) ? __expf(Sacc[ni][r]) : 0.0f;
                Plds[(quad * 4 + r) * 72 + ni * 16 + lrow] = f2bf(e);
                rs += e;
            }
            rs += __shfl_xor(rs, 1, 64);
            rs += __shfl_xor(rs, 2, 64);
            rs += __shfl_xor(rs, 4, 64);
            rs += __shfl_xor(rs, 8, 64);
            lacc[r] += rs;
        }
        wait_lds();   // same-wave P write->read: lgkmcnt(0) suffices, no barrier

        // PV: A = P from LDS, B = V^T from VR
        #pragma unroll
        for (int dc = 0; dc < 4; ++dc)
            #pragma unroll
            for (int s = 0; s < 2; ++s) {
                short8 af = *(const short8*)&Plds[lrow * 72 + (s * 4 + quad) * 8];
                #pragma unroll
                for (int ni = 0; ni < 4; ++ni) {
                    int n = ni * 16 + lrow;
                    short8 bf = *(const short8*)&VR[dc * 4096 + n * 64
                                + (((s * 4 + quad) ^ (n & 7)) << 3)];
                    Oacc[dc * 4 + ni] = __builtin_amdgcn_mfma_f32_16x16x32_bf16(
                        af, bf, Oacc[dc * 4 + ni], 0, 0, 0);
                }
            }
        __syncthreads();   // all waves done with KR/VR before next staging
    }

    // epilogue: O/l -> LDS repack -> coalesced 16B stores into ao
    u16* out = smem;    // 64 x 264 (spans dead KR + head of VR)
    float inv[4];
    #pragma unroll
    for (int r = 0; r < 4; ++r) inv[r] = 1.0f / lacc[r];
    #pragma unroll
    for (int dc = 0; dc < 4; ++dc)
        #pragma unroll
        for (int ni = 0; ni < 4; ++ni)
            #pragma unroll
            for (int r = 0; r < 4; ++r) {
                int row = wave * 16 + quad * 4 + r;
                int col = dc * 64 + ni * 16 + lrow;
                out[row * 264 + col] = f2bf(Oacc[dc * 4 + ni][r] * inv[r]);
            }
    __syncthreads();
    int zg = zoff + z;
    int b = zg >> 3, head = zg & 7;
    #pragma unroll
    for (int pp = 0; pp < 8; ++pp) {
        int row  = pp * 8 + (tid >> 5);
        int col8 = (tid & 31) * 8;
        uint4v w = *(const uint4v*)&out[row * 264 + col8];
        *(uint4v*)&ao[((long)(b * TPAD) + q0 + row) * 2048 + head * 256 + col8] = w;
    }
}

// ---------------------------------------------------------------------------
// LayerNorm: one wave per row of 256, fp32 in -> bf16 out
// ---------------------------------------------------------------------------
__global__ __launch_bounds__(256) void ln_k(const float* __restrict__ h,
                                            const u16* __restrict__ g,
                                            const u16* __restrict__ b,
                                            u16* __restrict__ out, int M) {
    int row  = blockIdx.x * 4 + (threadIdx.x >> 6);
    int lane = threadIdx.x & 63;
    if (row >= M) return;
    const float* x = h + (long)row * 256;
    float4v v = *(const float4v*)(x + lane * 4);
    float s  = v[0] + v[1] + v[2] + v[3];
    float s2 = v[0] * v[0] + v[1] * v[1] + v[2] * v[2] + v[3] * v[3];
    #pragma unroll
    for (int off = 32; off; off >>= 1) {
        s  += __shfl_xor(s, off, 64);
        s2 += __shfl_xor(s2, off, 64);
    }
    float mean = s * (1.0f / 256.0f);
    float var  = s2 * (1.0f / 256.0f) - mean * mean;
    float rs   = rsqrtf(var + 1e-5f);
    union { uint2v v; u16 e[4]; } o;
    #pragma unroll
    for (int j = 0; j < 4; ++j) {
        int c = lane * 4 + j;
        o.e[j] = f2bf((v[j] - mean) * rs * bf2f(g[c]) + bf2f(b[c]));
    }
    *(uint2v*)&out[(long)row * 256 + lane * 4] = o.v;
}

// ---------------------------------------------------------------------------
__global__ void embed_k(const u16* __restrict__ x, const u16* __restrict__ cls,
                        const u16* __restrict__ dict, float* __restrict__ h) {
    long i = (long)blockIdx.x * 256 + threadIdx.x;
    int d = i & 255;
    long row = i >> 8;
    int b = (int)(row / TPAD), t = (int)(row - (long)b * TPAD);
    float v;
    if (t < 1024)       v = bf2f(x[((long)b * 1024 + t) * 256 + d]);
    else if (t == 1024) v = bf2f(cls[d]);
    else if (t == 1025) v = bf2f(dict[d]);
    else                v = 0.0f;   // pad rows: zero (finite through LN)
    h[i] = v;
}

__global__ void outconv_k(const float* __restrict__ h, void* __restrict__ out,
                          const u32* __restrict__ flag) {
    long i = (long)blockIdx.x * 256 + threadIdx.x;
    int d = i & 255;
    long row = i >> 8;
    int b = (int)(row / TPAD), t = (int)(row - (long)b * TPAD);
    long o;
    if (t < 1024)       o = ((long)b * 1024 + t) * 256 + d;
    else if (t == 1024) o = 8L * 1024 * 256 + (long)b * 256 + d;
    else if (t == 1025) o = 8L * 1024 * 256 + 8L * 256 + (long)b * 256 + d;
    else return;
    float v = h[i];
    if (*flag) ((u16*)out)[o] = f2bf(v);
    else       ((float*)out)[o] = v;
}

// ---------------------------------------------------------------------------
template <int BM, int BN>
static void launch_gemm(hipStream_t s, const GP& p, int nz) {
    dim3 grid(p.N / BN, p.M / BM, nz);
    gemmNT_k<BM, BN><<<grid, dim3(256), 0, s>>>(p);
}

extern "C" void kernel_launch(void* const* d_in, const int* in_sizes, int n_in,
                              void* d_out, int out_size, void* d_ws, size_t ws_size,
                              hipStream_t stream) {
    char* ws = (char*)d_ws;
    size_t used = 0;
    auto alloc = [&](size_t bytes) {
        char* ptr = ws + used;
        used += (bytes + 255) & ~(size_t)255;
        return ptr;
    };
    u32* flag = (u32*)alloc(256);

    // plain bf16 canon for non-weight inputs (qkv bias handled separately)
    static const int plainIdx[10] = {0, 1, 2, 3, 4, 8, 9, 10, 12, 14};
    u16* cp[15] = {};
    for (int j = 0; j < 10; ++j) {
        int i = plainIdx[j];
        cp[i] = (u16*)alloc((size_t)in_sizes[i] * 2);
    }
    u16* qkv_bP  = (u16*)alloc(6L * 6144 * 2);          // permuted bias
    u16* qkv_wT  = (u16*)alloc(6L * 6144 * 256 * 2);    // permuted+transposed
    u16* proj_wT = (u16*)alloc(6L * 256 * 2048 * 2);
    u16* w1T     = (u16*)alloc(6L * 1024 * 256 * 2);
    u16* w2T     = (u16*)alloc(6L * 256 * 1024 * 2);

    float* h  = (float*)alloc((size_t)MPAD * 256 * 4);
    u16*   hn = (u16*)  alloc((size_t)MPAD * 256 * 2);
    u16*   ao = (u16*)  alloc((size_t)MPAD * 2048 * 2);
    u16*   mid= (u16*)  alloc((size_t)MPAD * 1024 * 2);

    // attention group size G (batches per group), adaptive to ws_size
    const size_t perB = (size_t)8 * 3L * TPAD * 256 * 2;   // q + k + vT per batch
    int G = 8;
    while (G > 1 && used + (size_t)G * perB + 8192 > ws_size) G >>= 1;
    u16* qb = (u16*)alloc((size_t)G * 8 * TPAD * 256 * 2);
    u16* kb = (u16*)alloc((size_t)G * 8 * TPAD * 256 * 2);
    u16* vT = (u16*)alloc((size_t)G * 8 * 256 * TPAD * 2);
    if (used > ws_size) {
        fprintf(stderr, "kernel_launch: need %zu ws bytes, have %zu\n", used, ws_size);
        return;
    }

    detect_k<<<1, 256, 0, stream>>>((const u32*)d_in[0], flag);
    for (int j = 0; j < 10; ++j) {
        int i = plainIdx[j];
        long n = in_sizes[i];
        convert_k<<<(int)((n + 255) / 256), 256, 0, stream>>>(d_in[i], cp[i], n, flag);
    }
    qkvbias_k<<<6 * 6144 / 256, 256, 0, stream>>>(d_in[6], qkv_bP, flag);
    transposeT_k<<<dim3(6144/32, 256/32, 6), dim3(32, 8), 0, stream>>>(d_in[5],  qkv_wT,  256,  6144, 1, flag);
    transposeT_k<<<dim3(256/32, 2048/32, 6), dim3(32, 8), 0, stream>>>(d_in[7],  proj_wT, 2048, 256,  0, flag);
    transposeT_k<<<dim3(1024/32, 256/32, 6), dim3(32, 8), 0, stream>>>(d_in[11], w1T,     256,  1024, 0, flag);
    transposeT_k<<<dim3(256/32, 1024/32, 6), dim3(32, 8), 0, stream>>>(d_in[13], w2T,     1024, 256,  0, flag);

    embed_k<<<MPAD, 256, 0, stream>>>(cp[0], cp[1], cp[2], h);

    const int nGroups = 8 / G;
    for (int l = 0; l < 6; ++l) {
        ln_k<<<MPAD / 4, 256, 0, stream>>>(h, cp[3] + l * 256, cp[4] + l * 256, hn, MPAD);

        for (int g = 0; g < nGroups; ++g) {
            {   // QKV: [G*1152, 256] x [6144, 256]^T -> Q/K rows, V^T
                GP p{};
                p.A = hn + (long)g * G * TPAD * 256;
                p.B = qkv_wT + (long)l * 6144 * 256;
                p.bias = qkv_bP + l * 6144;
                p.M = G * TPAD; p.N = 6144; p.K = 256;
                p.epi = 3; p.q = qb; p.k = kb; p.v = vT;
                launch_gemm<128, 128>(stream, p, 1);
            }
            // fused attention: 18 q-tiles x G*8 heads, XCD-swizzled 1D grid
            flash_k<<<dim3(18 * G * 8), dim3(256), 0, stream>>>(
                qb, kb, vT, ao, g * G * 8);
        }
        {   // proj: h = ao @ proj_w + b (fp32, 64x64 tiles: 576 blocks)
            GP p{};
            p.A = ao; p.B = proj_wT + (long)l * 256 * 2048;
            p.bias = cp[8] + l * 256;
            p.C = h; p.ldC = 256;
            p.M = MPAD; p.N = 256; p.K = 2048;
            p.epi = 0;
            launch_gemm<64, 64>(stream, p, 1);
        }
        ln_k<<<MPAD / 4, 256, 0, stream>>>(h, cp[9] + l * 256, cp[10] + l * 256, hn, MPAD);
        {   // mlp1: mid = gelu(hn @ w1 + b1) (bf16, repacked stores)
            GP p{};
            p.A = hn; p.B = w1T + (long)l * 1024 * 256;
            p.bias = cp[12] + l * 1024;
            p.C = mid;
            p.M = MPAD; p.N = 1024; p.K = 256;
            p.epi = 1;
            launch_gemm<128, 128>(stream, p, 1);
        }
        {   // mlp2: h = gelu(mid @ w2 + b2) (fp32, 64x64 tiles: 576 blocks)
            GP p{};
            p.A = mid; p.B = w2T + (long)l * 256 * 1024;
            p.bias = cp[14] + l * 256;
            p.C = h; p.ldC = 256;
            p.M = MPAD; p.N = 256; p.K = 1024;
            p.epi = 2;
            launch_gemm<64, 64>(stream, p, 1);
        }
    }

    outconv_k<<<MPAD, 256, 0, stream>>>(h, d_out, flag);
}